// Round 6
// baseline (422.213 us; speedup 1.0000x reference)
//
#include <hip/hip_runtime.h>
#include <hip/hip_bf16.h>
#include <cstdint>
#include <cstddef>

#define D 128
#define SBBITS 10                 // 1024 nodes per super-bucket
#define NSB 128                   // bucket slots (100000>>10 = 97 used)
#define TILE 4096                 // edges per k_bin block
#define BINT 512                  // threads in k_bin
#define NSLOT 64                  // stats atomic slots

typedef __attribute__((ext_vector_type(8))) short short8;
typedef __attribute__((ext_vector_type(4))) float f32x4;

__device__ __forceinline__ unsigned short f2bf(float f) {
    union { float f; unsigned u; } v; v.f = f;
    unsigned r = v.u + 0x7FFF + ((v.u >> 16) & 1);   // RNE
    return (unsigned short)(r >> 16);
}
__device__ __forceinline__ float bflo(unsigned p) {
    union { unsigned u; float f; } v; v.u = p << 16; return v.f;
}
__device__ __forceinline__ float bfhi(unsigned p) {
    union { unsigned u; float f; } v; v.u = p & 0xFFFF0000u; return v.f;
}

// ---- prep: detect int64 (b0), W->bf16 (all), zero g_sbcnt (b63) + part2 (slice b) ----
__global__ __launch_bounds__(256) void k_prep(const unsigned* __restrict__ ei, int E,
                                              int* __restrict__ flag,
                                              const float* __restrict__ W,
                                              unsigned short* __restrict__ Wbf,
                                              int* __restrict__ g_sbcnt,
                                              float* __restrict__ part2) {
    int t = threadIdx.x, b = blockIdx.x;
    int i = b * 256 + t;
    if (i < D * D) Wbf[i] = f2bf(W[i]);
    part2[i] = 0.f;                              // 64*256 = 16384 = D*D
    if (b == 0 && t == 0) {
        int n = E < 256 ? E : 256;
        int allz = 1;
        for (int k = 0; k < n; ++k) {
            if (ei[2 * k + 1] != 0u) { allz = 0; break; }
        }
        *flag = allz;
    }
    if (b == 63 && t < NSB) g_sbcnt[t] = 0;
}

// ---- GEMM: h[M][128] = x[M][128] @ W^T, bf16 MFMA, h stored bf16 ----
__global__ __launch_bounds__(256) void k_gemm(const float* __restrict__ x,
                                              const unsigned short* __restrict__ Wbf,
                                              unsigned short* __restrict__ h, int M) {
    int wave = threadIdx.x >> 6, lane = threadIdx.x & 63;
    int m0 = blockIdx.x * 64 + wave * 16;
    int lr = lane & 15;       // row-in-tile (A), col-in-tile (B/D)
    int lg = lane >> 4;       // k-group
    f32x4 acc[8];
#pragma unroll
    for (int i = 0; i < 8; ++i) acc[i] = (f32x4){0.f, 0.f, 0.f, 0.f};

    int row = m0 + lr;
    int rowc = row < M ? row : M - 1;
    const float* xr = x + (size_t)rowc * D;

#pragma unroll
    for (int ks = 0; ks < 4; ++ks) {
        int k0 = ks * 32 + lg * 8;
        float4 a0 = *(const float4*)(xr + k0);
        float4 a1 = *(const float4*)(xr + k0 + 4);
        short8 af;
        af[0] = (short)f2bf(a0.x); af[1] = (short)f2bf(a0.y);
        af[2] = (short)f2bf(a0.z); af[3] = (short)f2bf(a0.w);
        af[4] = (short)f2bf(a1.x); af[5] = (short)f2bf(a1.y);
        af[6] = (short)f2bf(a1.z); af[7] = (short)f2bf(a1.w);
#pragma unroll
        for (int nt = 0; nt < 8; ++nt) {
            short8 bf = *(const short8*)(Wbf + (size_t)(nt * 16 + lr) * D + k0);
            acc[nt] = __builtin_amdgcn_mfma_f32_16x16x32_bf16(af, bf, acc[nt], 0, 0, 0);
        }
    }
#pragma unroll
    for (int nt = 0; nt < 8; ++nt) {
#pragma unroll
        for (int r = 0; r < 4; ++r) {
            int rr = m0 + lg * 4 + r;
            if (rr < M) h[(size_t)rr * D + nt * 16 + lr] = f2bf(acc[nt][r]);
        }
    }
}

// ---- pass 1: tile-local LDS sort into 128 super-buckets, contiguous flush ----
// entry = src | (dstLocal << 17); src < 2^17, dstLocal < 1024
__global__ __launch_bounds__(BINT) void k_bin(const int* __restrict__ ei, int E,
                                              const int* __restrict__ flagp,
                                              int* __restrict__ g_sbcnt,
                                              unsigned* __restrict__ binned, int C2) {
    __shared__ unsigned stage[TILE];
    __shared__ unsigned char ssb[TILE];
    __shared__ int hcnt[NSB], hoff[NSB], lcur[NSB], gbase[NSB];
    int f64 = *flagp;
    int t = threadIdx.x;
    int base = blockIdx.x * TILE;
    int cnt = E - base; if (cnt > TILE) cnt = TILE;

    if (t < NSB) hcnt[t] = 0;
    __syncthreads();

    unsigned ent[8]; int esb[8];
#pragma unroll
    for (int j = 0; j < 8; ++j) {
        int idx = j * BINT + t;
        esb[j] = -1;
        if (idx < cnt) {
            int e = base + idx;
            int s, d;
            if (f64) { s = ei[2 * e]; d = ei[2 * (E + e)]; }
            else     { s = ei[e];     d = ei[E + e]; }
            esb[j] = d >> SBBITS;
            ent[j] = (unsigned)s | ((unsigned)(d & ((1 << SBBITS) - 1)) << 17);
            atomicAdd(&hcnt[esb[j]], 1);
        }
    }
    __syncthreads();
    if (t < NSB) hoff[t] = hcnt[t];
    __syncthreads();
#pragma unroll
    for (int off = 1; off < NSB; off <<= 1) {
        int a = (t < NSB && t >= off) ? hoff[t - off] : 0;
        __syncthreads();
        if (t < NSB) hoff[t] += a;
        __syncthreads();
    }
    if (t < NSB) {
        int ex = hoff[t] - hcnt[t];            // exclusive offset
        lcur[t] = ex;
        hoff[t] = ex;
        gbase[t] = (hcnt[t] > 0) ? atomicAdd(&g_sbcnt[t], hcnt[t]) : 0;
    }
    __syncthreads();
#pragma unroll
    for (int j = 0; j < 8; ++j) {
        if (esb[j] >= 0) {
            int p = atomicAdd(&lcur[esb[j]], 1);
            stage[p] = ent[j];
            ssb[p] = (unsigned char)esb[j];
        }
    }
    __syncthreads();
    for (int i = t; i < cnt; i += BINT) {      // lanes write consecutive addrs
        int sb = ssb[i];
        int pos = gbase[sb] + (i - hoff[sb]);
        if (pos < C2) binned[(size_t)sb * C2 + pos] = stage[i];
    }
}

// ---- pass 2: per-super-bucket degree/scan/fill within L2-resident window ----
__global__ __launch_bounds__(1024) void k_fill2(const unsigned* __restrict__ binned, int C2,
                                                const int* __restrict__ g_sbcnt,
                                                int2* __restrict__ ronode,
                                                float* __restrict__ dinv,
                                                int* __restrict__ csrc, int N) {
    __shared__ int deg[1024];
    __shared__ int scn[1024];
    __shared__ int cur[1024];
    int b = blockIdx.x, t = threadIdx.x;
    int cnt = g_sbcnt[b]; if (cnt > C2) cnt = C2;
    const unsigned* ent = binned + (size_t)b * C2;

    deg[t] = 0;
    __syncthreads();
    for (int i = t; i < cnt; i += 1024) atomicAdd(&deg[ent[i] >> 17], 1);
    __syncthreads();
    scn[t] = deg[t];
    __syncthreads();
    for (int off = 1; off < 1024; off <<= 1) {
        int a = (t >= off) ? scn[t - off] : 0;
        __syncthreads();
        scn[t] += a;
        __syncthreads();
    }
    int ex = scn[t] - deg[t];
    cur[t] = ex;
    int node = (b << SBBITS) + t;
    if (node < N) {
        ronode[node] = make_int2(b * C2 + ex, deg[t]);
        dinv[node] = deg[t] > 0 ? rsqrtf((float)deg[t]) : 0.0f;
    }
    __syncthreads();
    for (int i = t; i < cnt; i += 1024) {
        unsigned e = ent[i];
        int pos = atomicAdd(&cur[e >> 17], 1);
        csrc[b * C2 + pos] = (int)(e & 0x1FFFF);
    }
}

// ---- aggregation + fused BN partial stats ----
// 1 wave/node; dwordx2 loads cover 2 edges/instr; stats -> 64 atomic slots
__global__ __launch_bounds__(256) void k_agg(const unsigned long long* __restrict__ h,
                                             const int* __restrict__ csrc,
                                             const int2* __restrict__ ronode,
                                             const float* __restrict__ dinv,
                                             float4* __restrict__ out,
                                             float* __restrict__ part2, int N) {
    __shared__ float ssum[128], ssq[128];
    int t = threadIdx.x;
    int wave = t >> 6, lane = t & 63;
    int node = blockIdx.x * 4 + wave;
    int half = lane >> 5, lq = lane & 31;   // lq: 4-col group; half: edge parity
    if (t < 128) { ssum[t] = 0.f; ssq[t] = 0.f; }
    __syncthreads();

    float v0 = 0.f, v1 = 0.f, v2 = 0.f, v3 = 0.f;
    if (node < N) {
        int2 ro = ronode[node];
        int beg = ro.x, end = ro.x + ro.y;
        float a0 = 0.f, a1 = 0.f, a2 = 0.f, a3 = 0.f;
        int i = beg;
        for (; i + 16 <= end; i += 16) {
#pragma unroll
            for (int p = 0; p < 8; ++p) {
                int e = i + 2 * p + half;
                int s = csrc[e];
                float w = dinv[s];
                unsigned long long pk = h[(size_t)s * 32 + lq];
                unsigned lo = (unsigned)pk, hi = (unsigned)(pk >> 32);
                a0 += w * bflo(lo); a1 += w * bfhi(lo);
                a2 += w * bflo(hi); a3 += w * bfhi(hi);
            }
        }
        for (; i + 2 <= end; i += 2) {
            int e = i + half;
            int s = csrc[e];
            float w = dinv[s];
            unsigned long long pk = h[(size_t)s * 32 + lq];
            unsigned lo = (unsigned)pk, hi = (unsigned)(pk >> 32);
            a0 += w * bflo(lo); a1 += w * bfhi(lo);
            a2 += w * bflo(hi); a3 += w * bfhi(hi);
        }
        if (i < end) {                       // odd leftover: upper half weight 0
            int s = csrc[i];
            float w = half ? 0.f : dinv[s];
            unsigned long long pk = h[(size_t)s * 32 + lq];
            unsigned lo = (unsigned)pk, hi = (unsigned)(pk >> 32);
            a0 += w * bflo(lo); a1 += w * bfhi(lo);
            a2 += w * bflo(hi); a3 += w * bfhi(hi);
        }
        a0 += __shfl_xor(a0, 32);
        a1 += __shfl_xor(a1, 32);
        a2 += __shfl_xor(a2, 32);
        a3 += __shfl_xor(a3, 32);
        float sd = dinv[node];
        v0 = a0 * sd; v1 = a1 * sd; v2 = a2 * sd; v3 = a3 * sd;
        if (half == 0) {
            out[(size_t)node * 32 + lq] = make_float4(v0, v1, v2, v3);
            int c = lq * 4;
            atomicAdd(&ssum[c],     v0); atomicAdd(&ssq[c],     v0 * v0);
            atomicAdd(&ssum[c + 1], v1); atomicAdd(&ssq[c + 1], v1 * v1);
            atomicAdd(&ssum[c + 2], v2); atomicAdd(&ssq[c + 2], v2 * v2);
            atomicAdd(&ssum[c + 3], v3); atomicAdd(&ssq[c + 3], v3 * v3);
        }
    }
    __syncthreads();
    int slot = blockIdx.x & (NSLOT - 1);
    if (t < 128)            atomicAdd(&part2[slot * 256 + t],       ssum[t]);
    else if (t < 256)       atomicAdd(&part2[slot * 256 + t],       ssq[t - 128]);
}

// ---- reduce slots -> scale/shift params ----
__global__ void k_params(const float* __restrict__ part2, const float* __restrict__ gamma,
                         const float* __restrict__ beta, float* __restrict__ params, int N) {
    int t = threadIdx.x;   // 256
    float a = 0.f;
    for (int s = 0; s < NSLOT; ++s) a += part2[s * 256 + t];
    __shared__ float sh[256];
    sh[t] = a;
    __syncthreads();
    if (t < 128) {
        float mean = sh[t] / (float)N;
        float var = sh[128 + t] / (float)N - mean * mean;
        var = var > 0.f ? var : 0.f;
        float sc = gamma[t] * rsqrtf(var + 1e-5f);
        params[t] = sc;
        params[128 + t] = beta[t] - mean * sc;
    }
}

// ---- finalize in-place: out = relu(agg*scale+shift) + x ----
__global__ __launch_bounds__(256) void k_final(float4* __restrict__ out,
                                               const float4* __restrict__ x,
                                               const float* __restrict__ params, int n4) {
    const float4* p4 = (const float4*)params;
    for (int i = blockIdx.x * 256 + threadIdx.x; i < n4; i += gridDim.x * 256) {
        int c = i & 31;
        float4 s = p4[c], b = p4[32 + c];
        float4 v = out[i], xv = x[i];
        float4 r;
        r.x = fmaxf(v.x * s.x + b.x, 0.f) + xv.x;
        r.y = fmaxf(v.y * s.y + b.y, 0.f) + xv.y;
        r.z = fmaxf(v.z * s.z + b.z, 0.f) + xv.z;
        r.w = fmaxf(v.w * s.w + b.w, 0.f) + xv.w;
        out[i] = r;
    }
}

extern "C" void kernel_launch(void* const* d_in, const int* in_sizes, int n_in,
                              void* d_out, int out_size, void* d_ws, size_t ws_size,
                              hipStream_t stream) {
    const float* x     = (const float*)d_in[0];
    const int*   ei    = (const int*)d_in[1];
    const float* W     = (const float*)d_in[2];
    const float* gamma = (const float*)d_in[3];
    const float* beta  = (const float*)d_in[4];

    int N = in_sizes[0] / D;
    int E = in_sizes[1] / 2;
    int NSBu = (N + (1 << SBBITS) - 1) >> SBBITS;          // used super-buckets (<=NSB)
    int avg = (E + NSBu - 1) / NSBu;
    int C2 = ((avg + 4096 + 63) / 64) * 64;                // ~+22 sigma headroom

    char* ws = (char*)d_ws;
    size_t off = 0;
    auto alloc = [&](size_t bytes) { size_t o = off; off = (off + bytes + 255) & ~(size_t)255; return o; };

    unsigned short* h    = (unsigned short*)(ws + alloc((size_t)N * D * 2));
    int*      csrc   = (int*)     (ws + alloc((size_t)NSBu * C2 * 4));
    unsigned* binned = (unsigned*)(ws + alloc((size_t)NSBu * C2 * 4));
    int*      g_sbcnt= (int*)     (ws + alloc((size_t)NSB * 4));
    float*    dinv   = (float*)   (ws + alloc((size_t)N * 4));
    int2*     ronode = (int2*)    (ws + alloc((size_t)N * 8));
    float*    part2  = (float*)   (ws + alloc((size_t)NSLOT * 256 * 4));
    float*    params = (float*)   (ws + alloc(256 * 4));
    int*      flagp  = (int*)     (ws + alloc(4));
    unsigned short* Wbf = (unsigned short*)(ws + alloc((size_t)D * D * 2));

    k_prep<<<64, 256, 0, stream>>>((const unsigned*)ei, E, flagp, W, Wbf, g_sbcnt, part2);
    k_gemm<<<(N + 63) / 64, 256, 0, stream>>>(x, Wbf, h, N);
    k_bin<<<(E + TILE - 1) / TILE, BINT, 0, stream>>>(ei, E, flagp, g_sbcnt, binned, C2);
    k_fill2<<<NSBu, 1024, 0, stream>>>(binned, C2, g_sbcnt, ronode, dinv, csrc, N);
    k_agg<<<(N + 3) / 4, 256, 0, stream>>>((const unsigned long long*)h, csrc, ronode, dinv,
                                           (float4*)d_out, part2, N);
    k_params<<<1, 256, 0, stream>>>(part2, gamma, beta, params, N);
    k_final<<<2048, 256, 0, stream>>>((float4*)d_out, (const float4*)x, params,
                                      (N * D) / 4);
}

// Round 7
// 396.741 us; speedup vs baseline: 1.0642x; 1.0642x over previous
//
#include <hip/hip_runtime.h>
#include <hip/hip_bf16.h>
#include <cstdint>
#include <cstddef>

#define D 128
#define SBBITS 10                 // 1024 nodes per super-bucket
#define NSB 128                   // bucket slots (100000>>10 = 97 used)
#define TILE 4096                 // edges per k_bin block
#define BINT 512                  // threads in k_bin
#define NSLOT 64                  // stats atomic slots
#define AGGB 2048                 // k_agg persistent blocks

typedef __attribute__((ext_vector_type(8))) short short8;
typedef __attribute__((ext_vector_type(4))) float f32x4;

__device__ __forceinline__ unsigned short f2bf(float f) {
    union { float f; unsigned u; } v; v.f = f;
    unsigned r = v.u + 0x7FFF + ((v.u >> 16) & 1);   // RNE
    return (unsigned short)(r >> 16);
}
__device__ __forceinline__ float bflo(unsigned p) {
    union { unsigned u; float f; } v; v.u = p << 16; return v.f;
}
__device__ __forceinline__ float bfhi(unsigned p) {
    union { unsigned u; float f; } v; v.u = p & 0xFFFF0000u; return v.f;
}

// ---- prep: detect int64 (b0), W->bf16 (all), zero g_sbcnt (b63) + part2 (slice b) ----
__global__ __launch_bounds__(256) void k_prep(const unsigned* __restrict__ ei, int E,
                                              int* __restrict__ flag,
                                              const float* __restrict__ W,
                                              unsigned short* __restrict__ Wbf,
                                              int* __restrict__ g_sbcnt,
                                              float* __restrict__ part2) {
    int t = threadIdx.x, b = blockIdx.x;
    int i = b * 256 + t;
    if (i < D * D) Wbf[i] = f2bf(W[i]);
    part2[i] = 0.f;                              // 64*256 = 16384 = D*D
    if (b == 0 && t == 0) {
        int n = E < 256 ? E : 256;
        int allz = 1;
        for (int k = 0; k < n; ++k) {
            if (ei[2 * k + 1] != 0u) { allz = 0; break; }
        }
        *flag = allz;
    }
    if (b == 63 && t < NSB) g_sbcnt[t] = 0;
}

// ---- GEMM: h = x @ W^T (bf16 MFMA); x staged through LDS (coalesced) ----
__global__ __launch_bounds__(256) void k_gemm(const float* __restrict__ x,
                                              const unsigned short* __restrict__ Wbf,
                                              unsigned short* __restrict__ h, int M) {
    __shared__ unsigned short sx[64 * 136];      // 64 rows, pad 128->136 (bank spread)
    int t = threadIdx.x;
    int base = blockIdx.x * 64;

#pragma unroll
    for (int j = 0; j < 8; ++j) {
        int idx = j * 256 + t;                   // 2048 float4 chunks
        int row = idx >> 5, c4 = (idx & 31) * 4;
        int gr = base + row;
        float4 v = (gr < M) ? *(const float4*)(x + (size_t)gr * D + c4)
                            : make_float4(0.f, 0.f, 0.f, 0.f);
        unsigned short* dst = &sx[row * 136 + c4];
        dst[0] = f2bf(v.x); dst[1] = f2bf(v.y); dst[2] = f2bf(v.z); dst[3] = f2bf(v.w);
    }
    __syncthreads();

    int wave = t >> 6, lane = t & 63;
    int lr = lane & 15, lg = lane >> 4;
    int lrow = wave * 16 + lr;
    f32x4 acc[8];
#pragma unroll
    for (int i = 0; i < 8; ++i) acc[i] = (f32x4){0.f, 0.f, 0.f, 0.f};

#pragma unroll
    for (int ks = 0; ks < 4; ++ks) {
        int k0 = ks * 32 + lg * 8;
        short8 af = *(const short8*)(&sx[lrow * 136 + k0]);
#pragma unroll
        for (int nt = 0; nt < 8; ++nt) {
            short8 bf = *(const short8*)(Wbf + (size_t)(nt * 16 + lr) * D + k0);
            acc[nt] = __builtin_amdgcn_mfma_f32_16x16x32_bf16(af, bf, acc[nt], 0, 0, 0);
        }
    }
    int m0 = base + wave * 16;
#pragma unroll
    for (int nt = 0; nt < 8; ++nt) {
#pragma unroll
        for (int r = 0; r < 4; ++r) {
            int rr = m0 + lg * 4 + r;
            if (rr < M) h[(size_t)rr * D + nt * 16 + lr] = f2bf(acc[nt][r]);
        }
    }
}

// ---- pass 1: tile-local LDS sort into 128 super-buckets, contiguous flush ----
// entry = src | (dstLocal << 17); src < 2^17, dstLocal < 1024
__global__ __launch_bounds__(BINT) void k_bin(const int* __restrict__ ei, int E,
                                              const int* __restrict__ flagp,
                                              int* __restrict__ g_sbcnt,
                                              unsigned* __restrict__ binned, int C2) {
    __shared__ unsigned stage[TILE];
    __shared__ unsigned char ssb[TILE];
    __shared__ int hcnt[NSB], hoff[NSB], lcur[NSB], gbase[NSB];
    int f64 = *flagp;
    int t = threadIdx.x;
    int base = blockIdx.x * TILE;
    int cnt = E - base; if (cnt > TILE) cnt = TILE;

    if (t < NSB) hcnt[t] = 0;
    __syncthreads();

    unsigned ent[8]; int esb[8];
#pragma unroll
    for (int j = 0; j < 8; ++j) {
        int idx = j * BINT + t;
        esb[j] = -1;
        if (idx < cnt) {
            int e = base + idx;
            int s, d;
            if (f64) {
                s = ((const int2*)ei)[e].x;
                d = ((const int2*)ei)[E + e].x;
            } else {
                s = ei[e];
                d = ei[E + e];
            }
            esb[j] = d >> SBBITS;
            ent[j] = (unsigned)s | ((unsigned)(d & ((1 << SBBITS) - 1)) << 17);
            atomicAdd(&hcnt[esb[j]], 1);
        }
    }
    __syncthreads();
    if (t < NSB) hoff[t] = hcnt[t];
    __syncthreads();
#pragma unroll
    for (int off = 1; off < NSB; off <<= 1) {
        int a = (t < NSB && t >= off) ? hoff[t - off] : 0;
        __syncthreads();
        if (t < NSB) hoff[t] += a;
        __syncthreads();
    }
    if (t < NSB) {
        int ex = hoff[t] - hcnt[t];            // exclusive offset
        lcur[t] = ex;
        hoff[t] = ex;
        gbase[t] = (hcnt[t] > 0) ? atomicAdd(&g_sbcnt[t], hcnt[t]) : 0;
    }
    __syncthreads();
#pragma unroll
    for (int j = 0; j < 8; ++j) {
        if (esb[j] >= 0) {
            int p = atomicAdd(&lcur[esb[j]], 1);
            stage[p] = ent[j];
            ssb[p] = (unsigned char)esb[j];
        }
    }
    __syncthreads();
    for (int i = t; i < cnt; i += BINT) {      // lanes write consecutive addrs
        int sb = ssb[i];
        int pos = gbase[sb] + (i - hoff[sb]);
        if (pos < C2) binned[(size_t)sb * C2 + pos] = stage[i];
    }
}

// ---- pass 2: per-super-bucket degree/scan/fill within L2-resident window ----
__global__ __launch_bounds__(1024) void k_fill2(const unsigned* __restrict__ binned, int C2,
                                                const int* __restrict__ g_sbcnt,
                                                int2* __restrict__ ronode,
                                                float* __restrict__ dinv,
                                                int* __restrict__ csrc, int N) {
    __shared__ int deg[1024];
    __shared__ int scn[1024];
    __shared__ int cur[1024];
    int b = blockIdx.x, t = threadIdx.x;
    int cnt = g_sbcnt[b]; if (cnt > C2) cnt = C2;
    const unsigned* ent = binned + (size_t)b * C2;

    deg[t] = 0;
    __syncthreads();
    for (int i = t; i < cnt; i += 1024) atomicAdd(&deg[ent[i] >> 17], 1);
    __syncthreads();
    scn[t] = deg[t];
    __syncthreads();
    for (int off = 1; off < 1024; off <<= 1) {
        int a = (t >= off) ? scn[t - off] : 0;
        __syncthreads();
        scn[t] += a;
        __syncthreads();
    }
    int ex = scn[t] - deg[t];
    cur[t] = ex;
    int node = (b << SBBITS) + t;
    if (node < N) {
        ronode[node] = make_int2(b * C2 + ex, deg[t]);
        dinv[node] = deg[t] > 0 ? rsqrtf((float)deg[t]) : 0.0f;
    }
    __syncthreads();
    for (int i = t; i < cnt; i += 1024) {
        unsigned e = ent[i];
        int pos = atomicAdd(&cur[e >> 17], 1);
        csrc[b * C2 + pos] = (int)(e & 0x1FFFF);
    }
}

// ---- aggregation + register-accumulated BN stats (persistent grid-stride) ----
__global__ __launch_bounds__(256) void k_agg(const unsigned long long* __restrict__ h,
                                             const int* __restrict__ csrc,
                                             const int2* __restrict__ ronode,
                                             const float* __restrict__ dinv,
                                             float4* __restrict__ out,
                                             float* __restrict__ part2, int N) {
    __shared__ float ssum[128], ssq[128];
    int t = threadIdx.x;
    int wave = t >> 6, lane = t & 63;
    int half = lane >> 5, lq = lane & 31;   // lq: 4-col group; half: edge parity
    if (t < 128) { ssum[t] = 0.f; ssq[t] = 0.f; }

    float ps0 = 0.f, ps1 = 0.f, ps2 = 0.f, ps3 = 0.f;
    float pq0 = 0.f, pq1 = 0.f, pq2 = 0.f, pq3 = 0.f;

    for (int node = blockIdx.x * 4 + wave; node < N; node += AGGB * 4) {
        int2 ro = ronode[node];
        int beg = ro.x, end = ro.x + ro.y;
        float a0 = 0.f, a1 = 0.f, a2 = 0.f, a3 = 0.f;
        int i = beg;
        for (; i + 16 <= end; i += 16) {
#pragma unroll
            for (int p = 0; p < 8; ++p) {
                int e = i + 2 * p + half;
                int s = csrc[e];
                float w = dinv[s];
                unsigned long long pk = h[(size_t)s * 32 + lq];
                unsigned lo = (unsigned)pk, hi = (unsigned)(pk >> 32);
                a0 += w * bflo(lo); a1 += w * bfhi(lo);
                a2 += w * bflo(hi); a3 += w * bfhi(hi);
            }
        }
        for (; i + 2 <= end; i += 2) {
            int e = i + half;
            int s = csrc[e];
            float w = dinv[s];
            unsigned long long pk = h[(size_t)s * 32 + lq];
            unsigned lo = (unsigned)pk, hi = (unsigned)(pk >> 32);
            a0 += w * bflo(lo); a1 += w * bfhi(lo);
            a2 += w * bflo(hi); a3 += w * bfhi(hi);
        }
        if (i < end) {                       // odd leftover: upper half weight 0
            int s = csrc[i];
            float w = half ? 0.f : dinv[s];
            unsigned long long pk = h[(size_t)s * 32 + lq];
            unsigned lo = (unsigned)pk, hi = (unsigned)(pk >> 32);
            a0 += w * bflo(lo); a1 += w * bfhi(lo);
            a2 += w * bflo(hi); a3 += w * bfhi(hi);
        }
        a0 += __shfl_xor(a0, 32);
        a1 += __shfl_xor(a1, 32);
        a2 += __shfl_xor(a2, 32);
        a3 += __shfl_xor(a3, 32);
        float sd = dinv[node];
        float v0 = a0 * sd, v1 = a1 * sd, v2 = a2 * sd, v3 = a3 * sd;
        if (half == 0) {
            out[(size_t)node * 32 + lq] = make_float4(v0, v1, v2, v3);
            ps0 += v0; ps1 += v1; ps2 += v2; ps3 += v3;
            pq0 += v0 * v0; pq1 += v1 * v1; pq2 += v2 * v2; pq3 += v3 * v3;
        }
    }
    __syncthreads();
    if (half == 0) {
        int c = lq * 4;
        atomicAdd(&ssum[c],     ps0); atomicAdd(&ssq[c],     pq0);
        atomicAdd(&ssum[c + 1], ps1); atomicAdd(&ssq[c + 1], pq1);
        atomicAdd(&ssum[c + 2], ps2); atomicAdd(&ssq[c + 2], pq2);
        atomicAdd(&ssum[c + 3], ps3); atomicAdd(&ssq[c + 3], pq3);
    }
    __syncthreads();
    int slot = blockIdx.x & (NSLOT - 1);
    if (t < 128)       atomicAdd(&part2[slot * 256 + t], ssum[t]);
    else if (t < 256)  atomicAdd(&part2[slot * 256 + t], ssq[t - 128]);
}

// ---- reduce slots -> scale/shift params ----
__global__ void k_params(const float* __restrict__ part2, const float* __restrict__ gamma,
                         const float* __restrict__ beta, float* __restrict__ params, int N) {
    int t = threadIdx.x;   // 256
    float a = 0.f;
    for (int s = 0; s < NSLOT; ++s) a += part2[s * 256 + t];
    __shared__ float sh[256];
    sh[t] = a;
    __syncthreads();
    if (t < 128) {
        float mean = sh[t] / (float)N;
        float var = sh[128 + t] / (float)N - mean * mean;
        var = var > 0.f ? var : 0.f;
        float sc = gamma[t] * rsqrtf(var + 1e-5f);
        params[t] = sc;
        params[128 + t] = beta[t] - mean * sc;
    }
}

// ---- finalize in-place: out = relu(agg*scale+shift) + x ----
__global__ __launch_bounds__(256) void k_final(float4* __restrict__ out,
                                               const float4* __restrict__ x,
                                               const float* __restrict__ params, int n4) {
    const float4* p4 = (const float4*)params;
    for (int i = blockIdx.x * 256 + threadIdx.x; i < n4; i += gridDim.x * 256) {
        int c = i & 31;
        float4 s = p4[c], b = p4[32 + c];
        float4 v = out[i], xv = x[i];
        float4 r;
        r.x = fmaxf(v.x * s.x + b.x, 0.f) + xv.x;
        r.y = fmaxf(v.y * s.y + b.y, 0.f) + xv.y;
        r.z = fmaxf(v.z * s.z + b.z, 0.f) + xv.z;
        r.w = fmaxf(v.w * s.w + b.w, 0.f) + xv.w;
        out[i] = r;
    }
}

extern "C" void kernel_launch(void* const* d_in, const int* in_sizes, int n_in,
                              void* d_out, int out_size, void* d_ws, size_t ws_size,
                              hipStream_t stream) {
    const float* x     = (const float*)d_in[0];
    const int*   ei    = (const int*)d_in[1];
    const float* W     = (const float*)d_in[2];
    const float* gamma = (const float*)d_in[3];
    const float* beta  = (const float*)d_in[4];

    int N = in_sizes[0] / D;
    int E = in_sizes[1] / 2;
    int NSBu = (N + (1 << SBBITS) - 1) >> SBBITS;          // used super-buckets (<=NSB)
    int avg = (E + NSBu - 1) / NSBu;
    int C2 = ((avg + 4096 + 63) / 64) * 64;                // ~+22 sigma headroom

    char* ws = (char*)d_ws;
    size_t off = 0;
    auto alloc = [&](size_t bytes) { size_t o = off; off = (off + bytes + 255) & ~(size_t)255; return o; };

    unsigned short* h    = (unsigned short*)(ws + alloc((size_t)N * D * 2));
    int*      csrc   = (int*)     (ws + alloc((size_t)NSBu * C2 * 4));
    unsigned* binned = (unsigned*)(ws + alloc((size_t)NSBu * C2 * 4));
    int*      g_sbcnt= (int*)     (ws + alloc((size_t)NSB * 4));
    float*    dinv   = (float*)   (ws + alloc((size_t)N * 4));
    int2*     ronode = (int2*)    (ws + alloc((size_t)N * 8));
    float*    part2  = (float*)   (ws + alloc((size_t)NSLOT * 256 * 4));
    float*    params = (float*)   (ws + alloc(256 * 4));
    int*      flagp  = (int*)     (ws + alloc(4));
    unsigned short* Wbf = (unsigned short*)(ws + alloc((size_t)D * D * 2));

    k_prep<<<64, 256, 0, stream>>>((const unsigned*)ei, E, flagp, W, Wbf, g_sbcnt, part2);
    k_gemm<<<(N + 63) / 64, 256, 0, stream>>>(x, Wbf, h, N);
    k_bin<<<(E + TILE - 1) / TILE, BINT, 0, stream>>>(ei, E, flagp, g_sbcnt, binned, C2);
    k_fill2<<<NSBu, 1024, 0, stream>>>(binned, C2, g_sbcnt, ronode, dinv, csrc, N);
    k_agg<<<AGGB, 256, 0, stream>>>((const unsigned long long*)h, csrc, ronode, dinv,
                                    (float4*)d_out, part2, N);
    k_params<<<1, 256, 0, stream>>>(part2, gamma, beta, params, N);
    k_final<<<2048, 256, 0, stream>>>((float4*)d_out, (const float4*)x, params,
                                      (N * D) / 4);
}